// Round 3
// baseline (42.794 us; speedup 1.0000x reference)
//
#include <hip/hip_runtime.h>
#include <math.h>

#define BATCH 8192
#define NLEN 4096

// ---------------------------------------------------------------------------
// Kernel 1: ONE WAVE PER ROW (4 rows per 256-thread block), COALESCED loads.
// The row is split into 16 groups of 256 contiguous elements (1 KiB slabs);
// within group g, lane l owns the 4 contiguous elements at g*256 + l*4, so
// every global_load_dwordx4 is a perfect 64-lane x 16B = 1 KiB coalesced
// transaction (16 cache lines, vs 64 for the old 256B-strided layout).
//
// Compacted-sequence diff semantics preserved exactly: element order is
// (g, lane, k); in-group diffs serial over k; group boundary = my first
// valid vs last valid of nearest lower lane with a valid element (ballot +
// bpermute), falling back to the wave-uniform running tail from previous
// groups (run_last/run_has) when no lower lane in this group has one.
// ---------------------------------------------------------------------------
__global__ __launch_bounds__(256) void hrv_feats_kernel(
    const float* __restrict__ rr, float* __restrict__ feats) {
    const int lane = threadIdx.x & 63;
    const int wid = threadIdx.x >> 6;
    const int row = blockIdx.x * 4 + wid;
    const float* rbase = rr + (size_t)row * NLEN + lane * 4;

    double dsum = 0.0, dsumsq = 0.0, dsumd2 = 0.0;
    int cnt = 0, nn50 = 0;
    float run_last = 0.f;
    int run_has = 0;

#pragma unroll
    for (int half = 0; half < 2; ++half) {
        float4 v4[8];
#pragma unroll
        for (int ii = 0; ii < 8; ++ii)
            v4[ii] = *reinterpret_cast<const float4*>(rbase + (half * 8 + ii) * 256);

        float s = 0.f, s2 = 0.f, d2 = 0.f;  // f32 partials over <=32 elems
#pragma unroll
        for (int ii = 0; ii < 8; ++ii) {
            const float x[4] = {v4[ii].x, v4[ii].y, v4[ii].z, v4[ii].w};
            float first = 0.f, last = 0.f;
            int has = 0;
#pragma unroll
            for (int k = 0; k < 4; ++k) {
                float v = x[k];
                if (v > 0.f) {
                    s += v;
                    s2 += v * v;
                    ++cnt;
                    if (has) {
                        float d = v - last;  // same f32 sub as reference
                        d2 += d * d;
                        nn50 += (fabsf(d) > 0.05f) ? 1 : 0;
                    } else {
                        first = v;
                        has = 1;
                    }
                    last = v;
                }
            }
            // cross-lane boundary within this group
            unsigned long long m = __ballot(has != 0);
            unsigned long long pm = m & ((1ull << lane) - 1ull);  // lane0 -> 0
            int j = 63 - __clzll(pm | 1ull);
            float lastj = __shfl(last, j, 64);
            float pred = pm ? lastj : run_last;
            int pred_has = pm ? 1 : run_has;
            if (has && pred_has) {
                float d = first - pred;
                d2 += d * d;
                nn50 += (fabsf(d) > 0.05f) ? 1 : 0;
            }
            // advance wave-uniform running tail across groups
            if (m) {
                int jm = 63 - __clzll(m);
                run_last = __shfl(last, jm, 64);
                run_has = 1;
            }
        }
        dsum += s;
        dsumsq += s2;
        dsumd2 += d2;
    }

    // wave butterfly reduction (3 doubles + 2 ints)
#pragma unroll
    for (int off = 32; off; off >>= 1) {
        dsum += __shfl_down(dsum, off, 64);
        dsumsq += __shfl_down(dsumsq, off, 64);
        dsumd2 += __shfl_down(dsumd2, off, 64);
        cnt += __shfl_down(cnt, off, 64);
        nn50 += __shfl_down(nn50, off, 64);
    }

    if (lane == 0) {
        const float cntf = (float)cnt;
        const float denom_m = fmaxf(cntf, 1.f);
        const float mean = (float)(dsum / (double)denom_m);
        const float varsum = (float)(dsumsq - (double)cnt * (double)mean * (double)mean);
        const float denom_v = fmaxf(cntf - 1.f, 1.f);
        const float sdnn = sqrtf(fmaxf(varsum / denom_v, 0.f));
        const float rmssd = sqrtf(fmaxf((float)(dsumd2 / (double)denom_v), 0.f));
        const float pnn50 = (float)nn50 / denom_v;
        const float hr = 60.f / fmaxf(mean, 1e-12f);
        const float cv = sdnn / fmaxf(mean, 1e-12f);
        float f0 = mean, f1 = sdnn, f2 = rmssd, f3 = pnn50, f4 = hr, f5 = cv;
        if (cnt <= 1) { f0 = f1 = f2 = f3 = f4 = f5 = 0.f; }
        float* o = feats + row * 6;
        o[0] = f0; o[1] = f1; o[2] = f2;
        o[3] = f3; o[4] = f4; o[5] = f5;
    }
}

// ---------------------------------------------------------------------------
// Kernel 2 (fused col-stats + MLP): 32 blocks x 256 threads. Each block
// redundantly computes column mean/std/max over all 8192 rows (feats is
// 192 KiB, L2-resident), then applies normalize + 6->16 ReLU -> 32 MLP to
// its own 256 rows. Deterministic identical stats per block.
// ---------------------------------------------------------------------------
__global__ __launch_bounds__(256) void stats_mlp_kernel(
    const float* __restrict__ feats,
    const float* __restrict__ w1, const float* __restrict__ b1,
    const float* __restrict__ w2, const float* __restrict__ b2,
    float* __restrict__ out) {
    __shared__ double sh_s[4][6], sh_s2[4][6];
    __shared__ float sh_m[4][6];
    __shared__ float sh_stats[18];  // mean[6], std[6], max[6]

    const int t = threadIdx.x;
    double s[6] = {0, 0, 0, 0, 0, 0};
    double s2[6] = {0, 0, 0, 0, 0, 0};
    float mx[6] = {-INFINITY, -INFINITY, -INFINITY, -INFINITY, -INFINITY, -INFINITY};

#pragma unroll 4
    for (int i = t; i < BATCH; i += 256) {
        const float* fp = feats + i * 6;
#pragma unroll
        for (int c = 0; c < 6; ++c) {
            float f = fp[c];
            s[c] += (double)f;
            s2[c] += (double)f * (double)f;
            mx[c] = fmaxf(mx[c], f);
        }
    }
#pragma unroll
    for (int off = 32; off; off >>= 1) {
#pragma unroll
        for (int c = 0; c < 6; ++c) {
            s[c] += __shfl_down(s[c], off, 64);
            s2[c] += __shfl_down(s2[c], off, 64);
            mx[c] = fmaxf(mx[c], __shfl_down(mx[c], off, 64));
        }
    }
    if ((t & 63) == 0) {
        const int w = t >> 6;
#pragma unroll
        for (int c = 0; c < 6; ++c) {
            sh_s[w][c] = s[c];
            sh_s2[w][c] = s2[c];
            sh_m[w][c] = mx[c];
        }
    }
    __syncthreads();
    if (t < 6) {
        double S = 0, S2 = 0;
        float M = -INFINITY;
        for (int w = 0; w < 4; ++w) {
            S += sh_s[w][t];
            S2 += sh_s2[w][t];
            M = fmaxf(M, sh_m[w][t]);
        }
        const double meanb = S / (double)BATCH;
        double var = (S2 - (double)BATCH * meanb * meanb) / (double)(BATCH - 1);
        if (var < 0.0) var = 0.0;
        sh_stats[t] = (float)meanb;
        sh_stats[6 + t] = (float)sqrt(var);
        sh_stats[12 + t] = M;
    }
    __syncthreads();

    const int row = blockIdx.x * 256 + t;
    const float* fp = feats + row * 6;
    float f[6];
#pragma unroll
    for (int c = 0; c < 6; ++c) {
        float v = fp[c];
        if (sh_stats[12 + c] > 0.f) v = (v - sh_stats[c]) / (sh_stats[6 + c] + 1e-8f);
        f[c] = v;
    }
    float h[16];
#pragma unroll
    for (int j = 0; j < 16; ++j) {
        float a = b1[j];
#pragma unroll
        for (int c = 0; c < 6; ++c) a = fmaf(f[c], w1[c * 16 + j], a);
        h[j] = fmaxf(a, 0.f);
    }
    float o[32];
#pragma unroll
    for (int k = 0; k < 32; ++k) o[k] = b2[k];
#pragma unroll
    for (int j = 0; j < 16; ++j) {
        const float hj = h[j];
#pragma unroll
        for (int k = 0; k < 32; ++k) o[k] = fmaf(hj, w2[j * 32 + k], o[k]);
    }
    float4* ov = reinterpret_cast<float4*>(out + (size_t)row * 32);
    const float4* op = reinterpret_cast<const float4*>(o);
#pragma unroll
    for (int i = 0; i < 8; ++i) ov[i] = op[i];
}

extern "C" void kernel_launch(void* const* d_in, const int* in_sizes, int n_in,
                              void* d_out, int out_size, void* d_ws, size_t ws_size,
                              hipStream_t stream) {
    const float* rr = (const float*)d_in[0];
    const float* w1 = (const float*)d_in[1];
    const float* b1 = (const float*)d_in[2];
    const float* w2 = (const float*)d_in[3];
    const float* b2 = (const float*)d_in[4];
    float* out = (float*)d_out;
    float* feats = (float*)d_ws;  // BATCH*6 floats = 192 KiB

    hrv_feats_kernel<<<BATCH / 4, 256, 0, stream>>>(rr, feats);
    stats_mlp_kernel<<<BATCH / 256, 256, 0, stream>>>(feats, w1, b1, w2, b2, out);
}

// Round 4
// 42.539 us; speedup vs baseline: 1.0060x; 1.0060x over previous
//
#include <hip/hip_runtime.h>
#include <math.h>

#define BATCH 8192
#define NLEN 4096

// ---------------------------------------------------------------------------
// Kernel 1: ONE WAVE PER ROW (4 rows per 256-thread block). Lane l owns the
// contiguous 64-element chunk [l*64, l*64+64). BRANCHLESS inner loop:
// padding entries are exactly 0.0f, so sum/sumsq need NO mask (0 contributes
// 0); cnt/diffs use pure cndmask selects. This removes the per-element
// exec-mask branching (saveexec/cbranch ~8 ops + sched barrier per element)
// that made round-2/3 VALU-issue-bound instead of HBM-bound.
// Cross-lane compacted-diff boundary: one ballot + one variable shuffle per
// wave (nearest lower lane with a valid element).
// ---------------------------------------------------------------------------
__global__ __launch_bounds__(256) void hrv_feats_kernel(
    const float* __restrict__ rr, float* __restrict__ feats) {
    const int lane = threadIdx.x & 63;
    const int wid = threadIdx.x >> 6;
    const int row = blockIdx.x * 4 + wid;
    const float* r = rr + (size_t)row * NLEN + lane * 64;

    double dsum = 0.0, dsumsq = 0.0, dsumd2 = 0.0;
    int cnt = 0, nn50 = 0;
    float prev = 0.f, first = 0.f;
    bool has = false;

    float x[32];
    float4* xv = reinterpret_cast<float4*>(x);
    const float4* rv = reinterpret_cast<const float4*>(r);

#pragma unroll
    for (int half = 0; half < 2; ++half) {
#pragma unroll
        for (int i = 0; i < 8; ++i) xv[i] = rv[half * 8 + i];
#pragma unroll
        for (int c = 0; c < 2; ++c) {
            float s = 0.f, s2 = 0.f, d2 = 0.f;  // f32 partials over 16 elems
#pragma unroll
            for (int i = 0; i < 16; ++i) {
                const float v = x[c * 16 + i];
                const bool valid = v > 0.f;
                s += v;                    // padding is exactly 0 -> no mask
                s2 = fmaf(v, v, s2);
                cnt += valid ? 1 : 0;
                const float d = v - prev;  // same f32 sub as reference
                const float dm = (valid && has) ? d : 0.f;
                d2 = fmaf(dm, dm, d2);
                nn50 += (fabsf(dm) > 0.05f) ? 1 : 0;
                first = (valid && !has) ? v : first;
                prev = valid ? v : prev;
                has = has || valid;
            }
            dsum += s;
            dsumsq += s2;
            dsumd2 += d2;
        }
    }

    // boundary diff: my first valid vs last valid of nearest lower lane
    unsigned long long m = __ballot(has);
    unsigned long long pm = m & ((1ull << lane) - 1ull);  // lane0 -> 0
    int j = 63 - __clzll(pm | 1ull);
    float lastj = __shfl(prev, j, 64);
    if (has && pm) {
        float d = first - lastj;
        dsumd2 += (double)(d * d);
        nn50 += (fabsf(d) > 0.05f) ? 1 : 0;
    }

    // xor-butterfly reduction: ALL lanes end with totals (lanes 0-5 store)
#pragma unroll
    for (int off = 32; off; off >>= 1) {
        dsum += __shfl_xor(dsum, off, 64);
        dsumsq += __shfl_xor(dsumsq, off, 64);
        dsumd2 += __shfl_xor(dsumd2, off, 64);
        cnt += __shfl_xor(cnt, off, 64);
        nn50 += __shfl_xor(nn50, off, 64);
    }

    const float cntf = (float)cnt;
    const float denom_m = fmaxf(cntf, 1.f);
    const float mean = (float)(dsum / (double)denom_m);
    const float varsum = (float)(dsumsq - (double)cnt * (double)mean * (double)mean);
    const float denom_v = fmaxf(cntf - 1.f, 1.f);
    const float sdnn = sqrtf(fmaxf(varsum / denom_v, 0.f));
    const float rmssd = sqrtf(fmaxf((float)(dsumd2 / (double)denom_v), 0.f));
    const float pnn50 = (float)nn50 / denom_v;
    const float hr = 60.f / fmaxf(mean, 1e-12f);
    const float cv = sdnn / fmaxf(mean, 1e-12f);

    float val = mean;                    // lane 0
    val = (lane == 1) ? sdnn : val;
    val = (lane == 2) ? rmssd : val;
    val = (lane == 3) ? pnn50 : val;
    val = (lane == 4) ? hr : val;
    val = (lane == 5) ? cv : val;
    if (cnt <= 1) val = 0.f;
    // COLUMN-MAJOR: feats[c][row] -> coalesced stats reads in kernel 2
    if (lane < 6) feats[lane * BATCH + row] = val;
}

// ---------------------------------------------------------------------------
// Kernel 2 (fused col-stats + MLP): 32 blocks x 256 threads. Each block
// redundantly computes column mean/std(ddof=1)/max over the column-major
// feats (float4-coalesced, L2-resident, f64 accum for the catastrophic
// (sumsq - B*mean^2) cancellation), then applies normalize + 6->16 ReLU ->
// 32 MLP to its own 256 rows. Deterministic identical stats per block.
// ---------------------------------------------------------------------------
__global__ __launch_bounds__(256) void stats_mlp_kernel(
    const float* __restrict__ feats,
    const float* __restrict__ w1, const float* __restrict__ b1,
    const float* __restrict__ w2, const float* __restrict__ b2,
    float* __restrict__ out) {
    __shared__ double sh_s[4][6], sh_s2[4][6];
    __shared__ float sh_m[4][6];
    __shared__ float sh_stats[18];  // mean[6], std[6], max[6]

    const int t = threadIdx.x;
    double s[6], s2[6];
    float mx[6];
#pragma unroll
    for (int c = 0; c < 6; ++c) { s[c] = 0.0; s2[c] = 0.0; mx[c] = -INFINITY; }

#pragma unroll
    for (int c = 0; c < 6; ++c) {
        const float4* col = reinterpret_cast<const float4*>(feats + c * BATCH);
#pragma unroll
        for (int it = 0; it < BATCH / 4 / 256; ++it) {  // 8 iters
            float4 f4 = col[t + it * 256];
            const float f[4] = {f4.x, f4.y, f4.z, f4.w};
#pragma unroll
            for (int k = 0; k < 4; ++k) {
                s[c] += (double)f[k];
                s2[c] += (double)f[k] * (double)f[k];
                mx[c] = fmaxf(mx[c], f[k]);
            }
        }
    }
#pragma unroll
    for (int off = 32; off; off >>= 1) {
#pragma unroll
        for (int c = 0; c < 6; ++c) {
            s[c] += __shfl_down(s[c], off, 64);
            s2[c] += __shfl_down(s2[c], off, 64);
            mx[c] = fmaxf(mx[c], __shfl_down(mx[c], off, 64));
        }
    }
    if ((t & 63) == 0) {
        const int w = t >> 6;
#pragma unroll
        for (int c = 0; c < 6; ++c) {
            sh_s[w][c] = s[c];
            sh_s2[w][c] = s2[c];
            sh_m[w][c] = mx[c];
        }
    }
    __syncthreads();
    if (t < 6) {
        double S = 0, S2 = 0;
        float M = -INFINITY;
        for (int w = 0; w < 4; ++w) {
            S += sh_s[w][t];
            S2 += sh_s2[w][t];
            M = fmaxf(M, sh_m[w][t]);
        }
        const double meanb = S / (double)BATCH;
        double var = (S2 - (double)BATCH * meanb * meanb) / (double)(BATCH - 1);
        if (var < 0.0) var = 0.0;
        sh_stats[t] = (float)meanb;
        sh_stats[6 + t] = (float)sqrt(var);
        sh_stats[12 + t] = M;
    }
    __syncthreads();

    const int row = blockIdx.x * 256 + t;
    float f[6];
#pragma unroll
    for (int c = 0; c < 6; ++c) {
        float v = feats[c * BATCH + row];  // coalesced across threads
        if (sh_stats[12 + c] > 0.f) v = (v - sh_stats[c]) / (sh_stats[6 + c] + 1e-8f);
        f[c] = v;
    }
    float h[16];
#pragma unroll
    for (int j = 0; j < 16; ++j) {
        float a = b1[j];
#pragma unroll
        for (int c = 0; c < 6; ++c) a = fmaf(f[c], w1[c * 16 + j], a);
        h[j] = fmaxf(a, 0.f);
    }
    float o[32];
#pragma unroll
    for (int k = 0; k < 32; ++k) o[k] = b2[k];
#pragma unroll
    for (int j = 0; j < 16; ++j) {
        const float hj = h[j];
#pragma unroll
        for (int k = 0; k < 32; ++k) o[k] = fmaf(hj, w2[j * 32 + k], o[k]);
    }
    float4* ov = reinterpret_cast<float4*>(out + (size_t)row * 32);
    const float4* op = reinterpret_cast<const float4*>(o);
#pragma unroll
    for (int i = 0; i < 8; ++i) ov[i] = op[i];
}

extern "C" void kernel_launch(void* const* d_in, const int* in_sizes, int n_in,
                              void* d_out, int out_size, void* d_ws, size_t ws_size,
                              hipStream_t stream) {
    const float* rr = (const float*)d_in[0];
    const float* w1 = (const float*)d_in[1];
    const float* b1 = (const float*)d_in[2];
    const float* w2 = (const float*)d_in[3];
    const float* b2 = (const float*)d_in[4];
    float* out = (float*)d_out;
    float* feats = (float*)d_ws;  // column-major [6][BATCH] = 192 KiB

    hrv_feats_kernel<<<BATCH / 4, 256, 0, stream>>>(rr, feats);
    stats_mlp_kernel<<<BATCH / 256, 256, 0, stream>>>(feats, w1, b1, w2, b2, out);
}